// Round 1
// baseline (501.720 us; speedup 1.0000x reference)
//
#include <hip/hip_runtime.h>

#define B_   16
#define TXT  32
#define VID  2048
#define D_   256
#define S_   2080
#define SP   2176   // padded sequence (34*64)

typedef unsigned short ushort_t;
typedef __attribute__((ext_vector_type(8))) short short8;
typedef __attribute__((ext_vector_type(4))) short short4v;
typedef __attribute__((ext_vector_type(4))) float f32x4;

__device__ __forceinline__ ushort_t f2bf(float f) {
  unsigned u = __builtin_bit_cast(unsigned, f);
  unsigned r = (u + 0x7FFFu + ((u >> 16) & 1u)) >> 16;   // RNE (finite values)
  return (ushort_t)r;
}
__device__ __forceinline__ float bf2f(ushort_t h) {
  unsigned u = ((unsigned)h) << 16;
  return __builtin_bit_cast(float, u);
}

__device__ __forceinline__ void g2l16(void* lds, const void* g) {
  __builtin_amdgcn_global_load_lds(
      (const __attribute__((address_space(1))) char*)g,
      (__attribute__((address_space(3))) char*)lds, 16, 0, 0);
}

__device__ __forceinline__ f32x4 mfma16(short8 a, short8 b, f32x4 c) {
  return __builtin_amdgcn_mfma_f32_16x16x32_bf16(a, b, c, 0, 0, 0);
}

// ---------------- xpos table: [2048][128] x {cos*s, sin*s, cos/s, sin/s} ----------------
__global__ void tbl_kernel(float* __restrict__ tbl) {
  int idx = blockIdx.x * 256 + threadIdx.x;     // 2048*128 = 262144
  int n = idx >> 7, i = idx & 127;
  float invf = powf(10000.0f, -(float)i / 128.0f);
  float ang = (float)n * invf;
  float s, co;
  sincosf(ang, &s, &co);
  float sv = ((float)(2 * i) + 102.4f) / 358.4f;   // (2i + 0.4*256)/(1.4*256)
  float sc = powf(sv, (float)n / 512.0f);
  float4 r;
  r.x = co * sc; r.y = s * sc; r.z = co / sc; r.w = s / sc;
  *(float4*)(tbl + (size_t)idx * 4) = r;
}

// ---------------- sigmoid mask (bf16) + sparsity loss ----------------
__global__ void sig_loss_kernel(const float* __restrict__ learn, ushort_t* __restrict__ sigp,
                                float* __restrict__ loss) {
  const int tid = threadIdx.x;
  const int base = (blockIdx.x * 256 + tid) * 8;
  float4 v0 = *(const float4*)(learn + base);
  float4 v1 = *(const float4*)(learn + base + 4);
  float vals[8] = {v0.x, v0.y, v0.z, v0.w, v1.x, v1.y, v1.z, v1.w};
  float acc = 0.f;
  short8 sh;
  #pragma unroll
  for (int j = 0; j < 8; ++j) {
    int idx = base + j;
    float s = 1.0f / (1.0f + expf(-vals[j]));
    sh[j] = (short)f2bf(s);
    int rr = idx >> 11, cc = idx & 2047;
    if (rr != cc) acc += s;
  }
  *(short8*)(sigp + base) = sh;
  __shared__ float red[256];
  red[tid] = acc;
  __syncthreads();
  #pragma unroll
  for (int st = 128; st > 0; st >>= 1) {
    if (tid < st) red[tid] += red[tid + st];
    __syncthreads();
  }
  if (tid == 0) atomicAdd(loss, red[0] * (1.0f / 4194304.0f));
}

// ---------------- weight transpose: WT[mat][n][k] = W[k][n] (bf16) ----------------
__global__ void wt_kernel(const float* __restrict__ Wq, const float* __restrict__ Wk,
                          const float* __restrict__ Wv, ushort_t* __restrict__ WT) {
  __shared__ float t[64][68];
  const int k0 = blockIdx.x * 64, n0 = blockIdx.y * 64, mt = blockIdx.z;
  const float* W = (mt == 0) ? Wq : (mt == 1) ? Wk : Wv;
  int tid = threadIdx.x;
  int r = tid >> 4, cq = (tid & 15) * 4;
  #pragma unroll
  for (int m = 0; m < 4; ++m) {
    int k = m * 16 + r;
    float4 v = *(const float4*)(W + (size_t)(k0 + k) * 256 + n0 + cq);
    t[k][cq] = v.x; t[k][cq + 1] = v.y; t[k][cq + 2] = v.z; t[k][cq + 3] = v.w;
  }
  __syncthreads();
  #pragma unroll
  for (int m = 0; m < 4; ++m) {
    int n = m * 16 + r;
    short4v h;
    h[0] = (short)f2bf(t[cq + 0][n]);
    h[1] = (short)f2bf(t[cq + 1][n]);
    h[2] = (short)f2bf(t[cq + 2][n]);
    h[3] = (short)f2bf(t[cq + 3][n]);
    *(short4v*)(WT + ((size_t)mt * D_ + n0 + n) * D_ + k0 + cq) = h;
  }
}

// ---------------- txt rows: Q/K = (pos+x)W, V = xW ----------------
__global__ void txt_kernel(const float* __restrict__ src,
                           const float* __restrict__ Wq, const float* __restrict__ Wk,
                           const float* __restrict__ Wv,
                           ushort_t* __restrict__ Qp, ushort_t* __restrict__ Kp,
                           ushort_t* __restrict__ VTp) {
  __shared__ float a_s[8][256];
  __shared__ float x_s[8][256];
  const int tg = blockIdx.x;       // 0..3  (8 rows each)
  const int b  = blockIdx.y;
  const int c  = threadIdx.x;      // 0..255
  #pragma unroll
  for (int t = 0; t < 8; ++t) {
    int row = tg * 8 + t;
    float x = src[((size_t)b * S_ + row) * D_ + c];
    float xe = (float)(row + 1) * (6.283185307179586f / (32.0f + 1e-6f));
    int i = c >> 1;
    float dimt = powf(10000.0f, (2.0f * (float)i) / 256.0f);
    float ang = xe / dimt;
    float pv = (c & 1) ? cosf(ang) : sinf(ang);
    x_s[t][c] = x;
    a_s[t][c] = x + pv;
  }
  __syncthreads();
  float q[8] = {0,0,0,0,0,0,0,0}, k[8] = {0,0,0,0,0,0,0,0}, v[8] = {0,0,0,0,0,0,0,0};
  for (int kk = 0; kk < 256; ++kk) {
    float wq = Wq[(size_t)kk * 256 + c];
    float wk = Wk[(size_t)kk * 256 + c];
    float wv = Wv[(size_t)kk * 256 + c];
    #pragma unroll
    for (int t = 0; t < 8; ++t) {
      q[t] = fmaf(a_s[t][kk], wq, q[t]);
      k[t] = fmaf(a_s[t][kk], wk, k[t]);
      v[t] = fmaf(x_s[t][kk], wv, v[t]);
    }
  }
  #pragma unroll
  for (int t = 0; t < 8; ++t) {
    int row = tg * 8 + t;
    Qp[((size_t)b * SP + row) * D_ + c] = f2bf(q[t]);
    Kp[((size_t)b * SP + row) * D_ + c] = f2bf(k[t]);
    VTp[((size_t)b * D_ + c) * SP + row] = f2bf(v[t]);
  }
}

// ---------------- vid projection GEMM (+xpos epilogue, V transposed) ----------------
__global__ __launch_bounds__(256, 2) void vid_gemm(
    const float* __restrict__ src, const ushort_t* __restrict__ WT,
    const float* __restrict__ tbl,
    ushort_t* __restrict__ Qp, ushort_t* __restrict__ Kp, ushort_t* __restrict__ VTp) {
  __shared__ __align__(16) ushort_t ldsA[64 * 64];
  __shared__ __align__(16) ushort_t ldsB[64 * 64];

  const int rt = blockIdx.x;            // 0..31 row tiles (vid rows)
  const int b  = blockIdx.y;
  const int ct = blockIdx.z;            // 0..11 col tiles (3 mats x 4)
  const int nt = ct >> 2;
  const int n0 = (ct & 3) * 64;
  const int tid = threadIdx.x;
  const int wv = tid >> 6, lane = tid & 63, l15 = lane & 15, l4 = lane >> 4;

  f32x4 acc[4];
  #pragma unroll
  for (int t2 = 0; t2 < 4; ++t2) { acc[t2][0] = 0.f; acc[t2][1] = 0.f; acc[t2][2] = 0.f; acc[t2][3] = 0.f; }

  for (int kk = 0; kk < 256; kk += 64) {
    #pragma unroll
    for (int m = 0; m < 4; ++m) {                 // A tile 64x64 (f32->bf16, swizzled)
      int q = m * 256 + tid;
      int r = q >> 4;
      int kc = (q & 15) * 4;
      const float4 v = *(const float4*)(src + ((size_t)b * S_ + TXT + rt * 64 + r) * D_ + kk + kc);
      short4v h;
      h[0] = (short)f2bf(v.x); h[1] = (short)f2bf(v.y);
      h[2] = (short)f2bf(v.z); h[3] = (short)f2bf(v.w);
      int off = ((r << 7) + (kc << 1)) ^ ((r & 7) << 4);
      *(short4v*)((char*)ldsA + off) = h;
    }
    #pragma unroll
    for (int m = 0; m < 2; ++m) {                 // B^T tile 64x64 via global_load_lds
      int p = (m * 256 + tid) * 16;
      int nl = p >> 7;
      int c = (p & 127) ^ ((nl & 7) << 4);
      g2l16((char*)ldsB + p, (const char*)(WT + ((size_t)nt * D_ + n0 + nl) * D_ + kk) + c);
    }
    __syncthreads();
    #pragma unroll
    for (int ks = 0; ks < 2; ++ks) {
      int ar = wv * 16 + l15;
      int aoff = ((ar << 7) + ((ks * 32 + l4 * 8) << 1)) ^ ((ar & 7) << 4);
      short8 av = *(const short8*)((const char*)ldsA + aoff);
      #pragma unroll
      for (int t2 = 0; t2 < 4; ++t2) {
        int nl = t2 * 16 + l15;
        int boff = ((nl << 7) + ((ks * 32 + l4 * 8) << 1)) ^ ((nl & 7) << 4);
        short8 bv = *(const short8*)((const char*)ldsB + boff);
        acc[t2] = mfma16(av, bv, acc[t2]);
      }
    }
    __syncthreads();
  }

  const int rowl = wv * 16 + l4 * 4;
  if (nt < 2) {
    // xpos rotary epilogue; even col: x*cs - x_partner*ss ; odd: x*cs + x_partner*ss
    ushort_t* dst = (nt == 0) ? Qp : Kp;
    #pragma unroll
    for (int t2 = 0; t2 < 4; ++t2) {
      int c = n0 + t2 * 16 + l15;
      #pragma unroll
      for (int r = 0; r < 4; ++r) {
        int n = rt * 64 + rowl + r;          // vid position 0..2047
        float x = acc[t2][r];
        float xp = __shfl_xor(x, 1);
        const float4 tb = *(const float4*)(tbl + ((size_t)n * 128 + (c >> 1)) * 4);
        float cs = (nt == 0) ? tb.x : tb.z;
        float ss = (nt == 0) ? tb.y : tb.w;
        float val = (c & 1) ? fmaf(x, cs, xp * ss) : fmaf(x, cs, -xp * ss);
        dst[((size_t)b * SP + TXT + n) * D_ + c] = f2bf(val);
      }
    }
  } else {
    // V: transpose via LDS then coalesced store to VT
    #pragma unroll
    for (int t2 = 0; t2 < 4; ++t2)
      #pragma unroll
      for (int r = 0; r < 4; ++r) {
        int rr = rowl + r;
        int cc = t2 * 16 + l15;
        int off = ((rr << 7) + (cc << 1)) ^ ((rr & 7) << 4);
        *(ushort_t*)((char*)ldsA + off) = f2bf(acc[t2][r]);
      }
    __syncthreads();
    int n = tid >> 2;
    int rc = (tid & 3) * 16;
    short8 o0, o1;
    #pragma unroll
    for (int j = 0; j < 8; ++j) {
      int rr = rc + j;
      int off = ((rr << 7) + (n << 1)) ^ ((rr & 7) << 4);
      o0[j] = *(const short*)((const char*)ldsA + off);
    }
    #pragma unroll
    for (int j = 0; j < 8; ++j) {
      int rr = rc + 8 + j;
      int off = ((rr << 7) + (n << 1)) ^ ((rr & 7) << 4);
      o1[j] = *(const short*)((const char*)ldsA + off);
    }
    ushort_t* dst = VTp + ((size_t)b * D_ + n0 + n) * SP + TXT + rt * 64 + rc;
    *(short8*)dst = o0;
    *(short8*)(dst + 8) = o1;
  }
}

// ---------------- fused masked attention: out = (Q K^T * M) V ----------------
__global__ __launch_bounds__(256, 2) void attn_kernel(
    const ushort_t* __restrict__ Qp, const ushort_t* __restrict__ Kp,
    const ushort_t* __restrict__ VTp, const ushort_t* __restrict__ sigp,
    float* __restrict__ out) {
  __shared__ __align__(16) ushort_t ldsK[64 * 256];   // [kv][d]   swizzled (512B rows)
  __shared__ __align__(16) ushort_t ldsV[256 * 64];   // [d][kv]   swizzled (128B rows)
  __shared__ __align__(16) ushort_t ldsP[64 * 64];    // [q][kv]   swizzled (128B rows)

  const int qt = blockIdx.x;       // 0..32
  const int b  = blockIdx.y;
  const int tid = threadIdx.x;
  const int wv = tid >> 6;
  const int lane = tid & 63;
  const int l15 = lane & 15;
  const int l4  = lane >> 4;

  // Q fragments: wave owns q rows [qt*64 + wv*16, +16)
  short8 qf[8];
  {
    const ushort_t* qrow = Qp + ((size_t)b * SP + qt * 64 + wv * 16 + l15) * D_ + l4 * 8;
    #pragma unroll
    for (int ks = 0; ks < 8; ++ks) qf[ks] = *(const short8*)(qrow + ks * 32);
  }

  f32x4 oacc[16];
  #pragma unroll
  for (int dt = 0; dt < 16; ++dt) { oacc[dt][0] = 0.f; oacc[dt][1] = 0.f; oacc[dt][2] = 0.f; oacc[dt][3] = 0.f; }

  for (int kt = 0; kt < 33; ++kt) {
    #pragma unroll
    for (int m = 0; m < 8; ++m) {                 // stage K (pre-swizzled source)
      int p = (m * 256 + tid) * 16;
      int r = p >> 9;
      int c = (p & 511) ^ ((r & 7) << 4);
      g2l16((char*)ldsK + p, (const char*)(Kp + ((size_t)b * SP + kt * 64 + r) * D_) + c);
    }
    #pragma unroll
    for (int m = 0; m < 8; ++m) {                 // stage V^T
      int p = (m * 256 + tid) * 16;
      int d = p >> 7;
      int c = (p & 127) ^ ((d & 7) << 4);
      g2l16((char*)ldsV + p, (const char*)(VTp + ((size_t)b * D_ + d) * SP + kt * 64) + c);
    }
    __syncthreads();

    // S = Q K^T   (wave: 16 q-rows x 64 kv-cols)
    f32x4 sacc[4];
    #pragma unroll
    for (int ctt = 0; ctt < 4; ++ctt) { sacc[ctt][0] = 0.f; sacc[ctt][1] = 0.f; sacc[ctt][2] = 0.f; sacc[ctt][3] = 0.f; }
    #pragma unroll
    for (int ks = 0; ks < 8; ++ks) {
      #pragma unroll
      for (int ctt = 0; ctt < 4; ++ctt) {
        int row = ctt * 16 + l15;
        int off = ((row << 9) + ((ks * 32 + l4 * 8) << 1)) ^ ((row & 7) << 4);
        short8 kf = *(const short8*)((const char*)ldsK + off);
        sacc[ctt] = mfma16(qf[ks], kf, sacc[ctt]);
      }
    }

    // mask + P (bf16 in LDS, wave-local rows)
    #pragma unroll
    for (int ctt = 0; ctt < 4; ++ctt) {
      int kvg = kt * 64 + ctt * 16 + l15;
      bool kvv = (kvg >= TXT) && (kvg < S_);
      #pragma unroll
      for (int r = 0; r < 4; ++r) {
        int qg = qt * 64 + wv * 16 + l4 * 4 + r;
        float mv = 1.0f;
        if (kvv && qg >= TXT && qg < S_)
          mv = bf2f(sigp[(size_t)(qg - TXT) * VID + (kvg - TXT)]);
        float pvv = sacc[ctt][r] * mv;
        int prow = wv * 16 + l4 * 4 + r;
        int pcol = ctt * 16 + l15;
        int off = ((prow << 7) + (pcol << 1)) ^ ((prow & 7) << 4);
        *(ushort_t*)((char*)ldsP + off) = f2bf(pvv);
      }
    }

    // O += P V
    #pragma unroll
    for (int ks = 0; ks < 2; ++ks) {
      int prow = wv * 16 + l15;
      int poff = ((prow << 7) + ((ks * 32 + l4 * 8) << 1)) ^ ((prow & 7) << 4);
      short8 pf = *(const short8*)((const char*)ldsP + poff);
      #pragma unroll
      for (int dt = 0; dt < 16; ++dt) {
        int dd = dt * 16 + l15;
        int voff = ((dd << 7) + ((ks * 32 + l4 * 8) << 1)) ^ ((dd & 7) << 4);
        short8 vf = *(const short8*)((const char*)ldsV + voff);
        oacc[dt] = mfma16(pf, vf, oacc[dt]);
      }
    }
    __syncthreads();
  }

  #pragma unroll
  for (int dt = 0; dt < 16; ++dt) {
    int dd = dt * 16 + l15;
    #pragma unroll
    for (int r = 0; r < 4; ++r) {
      int qg = qt * 64 + wv * 16 + l4 * 4 + r;
      if (qg < S_)
        out[((size_t)b * S_ + qg) * D_ + dd] = oacc[dt][r];
    }
  }
}

extern "C" void kernel_launch(void* const* d_in, const int* in_sizes, int n_in,
                              void* d_out, int out_size, void* d_ws, size_t ws_size,
                              hipStream_t stream) {
  (void)in_sizes; (void)n_in; (void)out_size; (void)ws_size;
  const float* src   = (const float*)d_in[0];
  const float* learn = (const float*)d_in[1];
  const float* Wtq = (const float*)d_in[2];
  const float* Wtk = (const float*)d_in[3];
  const float* Wtv = (const float*)d_in[4];
  const float* Wvq = (const float*)d_in[5];
  const float* Wvk = (const float*)d_in[6];
  const float* Wvv = (const float*)d_in[7];
  float* out = (float*)d_out;

  char* ws = (char*)d_ws;
  const size_t QKV_ONE = (size_t)B_ * SP * D_ * 2;         // 17,825,792 B each
  const size_t QP_OFF  = 0;
  const size_t KP_OFF  = QP_OFF + QKV_ONE;
  const size_t VT_OFF  = KP_OFF + QKV_ONE;
  const size_t SIG_OFF = VT_OFF + QKV_ONE;                  // 53,477,376
  const size_t TBL_OFF = SIG_OFF + (size_t)VID * VID * 2;   // +8,388,608
  const size_t WT_OFF  = TBL_OFF + (size_t)VID * 128 * 4 * sizeof(float); // +4,194,304
  // total ws use: WT_OFF + 393,216 = 66,453,504 B

  ushort_t* Qp   = (ushort_t*)(ws + QP_OFF);
  ushort_t* Kp   = (ushort_t*)(ws + KP_OFF);
  ushort_t* VTp  = (ushort_t*)(ws + VT_OFF);
  ushort_t* sigp = (ushort_t*)(ws + SIG_OFF);
  float*    tbl  = (float*)(ws + TBL_OFF);
  ushort_t* WT   = (ushort_t*)(ws + WT_OFF);

  float* loss = out + (size_t)B_ * S_ * D_;

  hipMemsetAsync(ws, 0, SIG_OFF, stream);          // zero Q/K/VT (padding rows)
  hipMemsetAsync(loss, 0, sizeof(float), stream);

  tbl_kernel<<<1024, 256, 0, stream>>>(tbl);
  sig_loss_kernel<<<2048, 256, 0, stream>>>(learn, sigp, loss);
  wt_kernel<<<dim3(4, 4, 3), 256, 0, stream>>>(Wvq, Wvk, Wvv, WT);
  txt_kernel<<<dim3(4, B_), 256, 0, stream>>>(src, Wtq, Wtk, Wtv, Qp, Kp, VTp);
  vid_gemm<<<dim3(32, B_, 12), 256, 0, stream>>>(src, WT, tbl, Qp, Kp, VTp);
  attn_kernel<<<dim3(33, B_), 256, 0, stream>>>(Qp, Kp, VTp, sigp, out);
}